// Round 7
// baseline (1708.033 us; speedup 1.0000x reference)
//
#include <hip/hip_runtime.h>

#define DH    20       // hidden width
#define BKSC  10       // log2 nodes per COARSE bucket (sort granularity)
#define BKC   1024     // nodes per coarse bucket
#define MAXKC 128      // max coarse buckets (N=100000 -> KC=98)
#define MAXNB 512      // max chunk blocks (E=3.2M/8192 -> 391)
#define BKSF  8        // log2 nodes per FINE bucket (build granularity)
#define BKF   256      // nodes per fine bucket
#define ECAP  10240    // LDS col-staging capacity per fine bucket (avg ~8.2K)
#define CHUNK 8192     // edges per hist/place block

// ---------------- setup kernels ----------------

// one read pass over src+dst; per-block histograms stored to global (no atomics)
__global__ __launch_bounds__(256) void bucket_hist2(const int* __restrict__ src,
        const int* __restrict__ dst, int* __restrict__ pbh_d,
        int* __restrict__ pbh_s, int E, int K) {
    __shared__ int hd[MAXKC];
    __shared__ int hs[MAXKC];
    for (int i = threadIdx.x; i < K; i += blockDim.x) { hd[i] = 0; hs[i] = 0; }
    __syncthreads();
    int lo = blockIdx.x * CHUNK;
    int hi = lo + CHUNK; if (hi > E) hi = E;
    for (int e = lo + (int)threadIdx.x; e < hi; e += 256) {
        atomicAdd(&hd[__builtin_nontemporal_load(&dst[e]) >> BKSC], 1);
        atomicAdd(&hs[__builtin_nontemporal_load(&src[e]) >> BKSC], 1);
    }
    __syncthreads();
    for (int i = threadIdx.x; i < K; i += blockDim.x) {
        pbh_d[blockIdx.x * MAXKC + i] = hd[i];
        pbh_s[blockIdx.x * MAXKC + i] = hs[i];
    }
}

// radix scan: per-(block,bucket) global bases. Thread k (<128) owns dst-bucket
// column k; thread 128+k owns src-bucket column k. Column sum -> half-block
// scan -> bucket base -> rewrite column with running global offsets.
__global__ __launch_bounds__(256) void pb_scan(int* __restrict__ pbh_d,
        int* __restrict__ pbh_s, int* __restrict__ bbase_d,
        int* __restrict__ bbase_s, int NB, int K) {
    __shared__ int a[256];
    int t = threadIdx.x;
    int k = t & 127;
    int* pbh   = (t < 128) ? pbh_d : pbh_s;
    int* bbase = (t < 128) ? bbase_d : bbase_s;
    int tot = 0;
    if (k < K)
        for (int b = 0; b < NB; ++b) tot += pbh[b * MAXKC + k];
    a[t] = (k < K) ? tot : 0;
    __syncthreads();
    for (int off = 1; off < 128; off <<= 1) {
        int v = (k >= off) ? a[t - off] : 0;
        __syncthreads();
        a[t] += v;
        __syncthreads();
    }
    if (k < K) {
        int run = a[t] - tot;                 // exclusive bucket base
        bbase[k] = run;
        if (k == K - 1) bbase[K] = a[t];      // grand total
        for (int b = 0; b < NB; ++b) {
            int c = pbh[b * MAXKC + k];
            pbh[b * MAXKC + k] = run;         // this block's global base
            run += c;
        }
    }
}

// one-pass counting place: LDS cursors pre-seeded with exact global bases
// (no re-histogram, no global cursor atomics). pairs = (src<<10|dst&1023)
// dst-sorted; ssort = src&1023 src-sorted.
__global__ __launch_bounds__(256) void bucket_place(const int* __restrict__ src,
        const int* __restrict__ dst, const int* __restrict__ pbh_d,
        const int* __restrict__ pbh_s, int* __restrict__ pairs,
        int* __restrict__ ssort, int E, int K) {
    __shared__ int cd[MAXKC];
    __shared__ int cs[MAXKC];
    for (int i = threadIdx.x; i < K; i += blockDim.x) {
        cd[i] = pbh_d[blockIdx.x * MAXKC + i];
        cs[i] = pbh_s[blockIdx.x * MAXKC + i];
    }
    __syncthreads();
    int lo = blockIdx.x * CHUNK;
    int hi = lo + CHUNK; if (hi > E) hi = E;
    for (int e = lo + (int)threadIdx.x; e < hi; e += 256) {
        int d = __builtin_nontemporal_load(&dst[e]);
        int s = __builtin_nontemporal_load(&src[e]);
        int pd = atomicAdd(&cd[d >> BKSC], 1);          // LDS atomic
        pairs[pd] = (s << BKSC) | (d & (BKC - 1));      // src<2^17 -> 27 bits
        int ps = atomicAdd(&cs[s >> BKSC], 1);
        ssort[ps] = s & (BKC - 1);
    }
}

// per-coarse-src-bucket LDS histogram over its ssort segment -> dout
__global__ __launch_bounds__(256) void bucket_outdeg(const int* __restrict__ bbase_s,
        const int* __restrict__ ssort, double* __restrict__ dout, int n_nodes) {
    __shared__ int h[BKC];
    int k = blockIdx.x;
    int t = threadIdx.x;
    int nbase = k << BKSC;
    int nrem = n_nodes - nbase; if (nrem > BKC) nrem = BKC;
    for (int i = t; i < BKC; i += 256) h[i] = 1;   // self loop
    __syncthreads();
    int e0 = bbase_s[k], e1 = bbase_s[k + 1];
    for (int e = e0 + t; e < e1; e += 256)
        atomicAdd(&h[__builtin_nontemporal_load(&ssort[e])], 1);
    __syncthreads();
    for (int i = t; i < nrem; i += 256)
        dout[nbase + i] = 1.0 / sqrt((double)h[i]);
}

// FINE-granularity build (391 blocks for occupancy) over the COARSE-sorted
// pairs: fine block k filters its quarter of coarse segment k>>2 in two
// L2-hot passes. Pass 1: fine histogram + 'before' count -> global base.
// Block scan -> row_ptr + din. Pass 2: scatter into LDS staging, stream out
// as contiguous full lines. XCD-chunked swizzle keeps sibling fine blocks on
// one XCD so the coarse segment stays L2-resident.
__global__ __launch_bounds__(256) void bucket_build(
        const int* __restrict__ bbase, const int* __restrict__ pairs,
        int* __restrict__ row_ptr, double* __restrict__ din,
        int* __restrict__ col, int n_nodes, int n_edges) {
    __shared__ int h[BKF];
    __shared__ int ts[BKF];
    __shared__ int red[256];
    __shared__ int ecol[ECAP];
    int nwg = gridDim.x;
    int xcd = blockIdx.x & 7;
    int loc = blockIdx.x >> 3;
    int q = nwg >> 3, r = nwg & 7;
    int k = ((xcd < r) ? xcd * (q + 1) : r * (q + 1) + (xcd - r) * q) + loc;
    int kc = k >> 2;             // coarse bucket
    int f  = k & 3;              // quarter within coarse bucket
    int t = threadIdx.x;
    int nbase = k << BKSF;
    int nrem = n_nodes - nbase; if (nrem > BKF) nrem = BKF;
    h[t] = 0;
    __syncthreads();
    int e0 = bbase[kc], e1 = bbase[kc + 1];
    int before = 0;
    for (int e = e0 + t; e < e1; e += 256) {
        int pk = pairs[e];                    // plain load: re-read, keep cached
        int dl = pk & (BKC - 1);
        int fe = dl >> BKSF;
        if (fe == f) atomicAdd(&h[dl & (BKF - 1)], 1);
        else if (fe < f) ++before;
    }
    red[t] = before;
    __syncthreads();
    for (int off = 128; off > 0; off >>= 1) {
        if (t < off) red[t] += red[t + off];
        __syncthreads();
    }
    int fbase = e0 + red[0];                  // global base of this fine segment
    int c = h[t];
    ts[t] = c;
    __syncthreads();
    for (int off = 1; off < 256; off <<= 1) {
        int v = (t >= off) ? ts[t - off] : 0;
        __syncthreads();
        ts[t] += v;
        __syncthreads();
    }
    int lx = ts[t] - c;                       // fine-local exclusive prefix
    if (t < nrem) {
        row_ptr[nbase + t] = fbase + lx;
        din[nbase + t] = 1.0 / sqrt((double)(c + 1));   // +1 self loop
    }
    h[t] = lx;                                // fine-local cursor into ecol
    if (t == 0 && nbase + BKF >= n_nodes) row_ptr[n_nodes] = n_edges;
    __syncthreads();
    for (int e = e0 + t; e < e1; e += 256) {
        int pk = pairs[e];
        int dl = pk & (BKC - 1);
        if ((dl >> BKSF) == f) {
            int slot = atomicAdd(&h[dl & (BKF - 1)], 1);    // LDS atomic
            if (slot < ECAP) ecol[slot] = pk >> BKSC;
            else col[fbase + slot] = pk >> BKSC;            // overflow guard
        }
    }
    __syncthreads();
    int cnt = ts[BKF - 1];
    int lim = cnt < ECAP ? cnt : ECAP;
    for (int i = t; i < lim; i += 256)        // contiguous full-line stream-out
        col[fbase + i] = ecol[i];
}

// ---------------- layer kernels ----------------

// x0[n] = feat[n] * dout[n]   (layer 0 input is N x 1)
__global__ void compute_x0(const float* __restrict__ feat, const double* __restrict__ dout,
                           double* __restrict__ x0, int n) {
    int i = blockIdx.x * blockDim.x + threadIdx.x;
    if (i < n) x0[i] = (double)feat[i] * dout[i];
}

// layer 0: g[n] = x0[n] + sum_{s in N(n)} x0[s]  (scalar gather, 64 lanes edge-parallel)
__global__ __launch_bounds__(256) void layer_start(
        const double* __restrict__ x0, const int* __restrict__ row_ptr,
        const int* __restrict__ col, const double* __restrict__ din,
        const double* __restrict__ dout, const float* __restrict__ W,
        const float* __restrict__ b, float* __restrict__ xout, int n_nodes) {
    int n    = (blockIdx.x * blockDim.x + threadIdx.x) >> 6;   // one wave per node
    int lane = threadIdx.x & 63;
    if (n >= n_nodes) return;
    double a = (lane == 0) ? x0[n] : 0.0;   // self loop
    int e0 = row_ptr[n], e1 = row_ptr[n + 1];
    for (int e = e0 + lane; e < e1; e += 64)
        a += x0[__builtin_nontemporal_load(&col[e])];
#pragma unroll
    for (int off = 32; off > 0; off >>= 1)
        a += __shfl_xor(a, off, 64);
    if (lane < DH) {
        double v = a * din[n] * (double)W[lane] + (double)b[lane];
        float r = fmaxf((float)v, 0.0f);
        xout[(long)n * DH + lane] = (float)((double)r * dout[n]);
    }
}

// dense transform: y[n] = h'[n] @ W   (h' already carries the dout scaling).
__global__ __launch_bounds__(256) void transform(
        const float* __restrict__ h, const float* __restrict__ W,
        float* __restrict__ y, int n_nodes) {
    __shared__ float Wl[DH * DH];
    for (int i = threadIdx.x; i < DH * DH; i += blockDim.x) Wl[i] = W[i];
    __syncthreads();
    int n = blockIdx.x * blockDim.x + threadIdx.x;
    if (n >= n_nodes) return;
    const float4* h4 = (const float4*)(h + (size_t)n * DH);
    float4 a0 = h4[0], a1 = h4[1], a2 = h4[2], a3 = h4[3], a4 = h4[4];
    float hv[DH] = {a0.x, a0.y, a0.z, a0.w, a1.x, a1.y, a1.z, a1.w,
                    a2.x, a2.y, a2.z, a2.w, a3.x, a3.y, a3.z, a3.w,
                    a4.x, a4.y, a4.z, a4.w};
    double acc[DH];
#pragma unroll
    for (int j = 0; j < DH; ++j) acc[j] = 0.0;
#pragma unroll
    for (int k = 0; k < DH; ++k) {
        double hk = (double)hv[k];
#pragma unroll
        for (int j = 0; j < DH; ++j)
            acc[j] += hk * (double)Wl[k * DH + j];   // LDS broadcast, conflict-free
    }
    float4* y4 = (float4*)(y + (size_t)n * DH);
    y4[0] = make_float4((float)acc[0],  (float)acc[1],  (float)acc[2],  (float)acc[3]);
    y4[1] = make_float4((float)acc[4],  (float)acc[5],  (float)acc[6],  (float)acc[7]);
    y4[2] = make_float4((float)acc[8],  (float)acc[9],  (float)acc[10], (float)acc[11]);
    y4[3] = make_float4((float)acc[12], (float)acc[13], (float)acc[14], (float)acc[15]);
    y4[4] = make_float4((float)acc[16], (float)acc[17], (float)acc[18], (float)acc[19]);
}

// gather+aggregate: h'[n] = relu(din[n]*(y[n] + sum_{s in N(n)} y[s]) + b) * dout[n]
// Per-slot accumulation in f64; single convert to f32 before the folds halves
// the cross-lane traffic (shfl double = 2 ds_bpermute; f32 = 1).
__global__ __launch_bounds__(256, 8) void gather_agg(
        const float* __restrict__ y, const int* __restrict__ row_ptr,
        const int* __restrict__ col, const double* __restrict__ din,
        const double* __restrict__ dout, const float* __restrict__ b,
        float* __restrict__ hout, int n_nodes, int mode) {
    int n    = (blockIdx.x * blockDim.x + threadIdx.x) >> 6;   // one wave per node
    int lane = threadIdx.x & 63;
    if (n >= n_nodes) return;

    int ep = lane / 5;           // edge slot 0..12 (lanes 60..63 -> ep=12, inactive)
    int jq = lane - ep * 5;      // float4 quarter 0..4
    const float4* __restrict__ y4 = (const float4*)y;

    int e0 = row_ptr[n], e1 = row_ptr[n + 1];

    int s0 = -1, s1 = -1, s2 = -1, s3 = -1;
    if (ep < 12) {
        int p = e0 + ep;
        if (p      < e1) s0 = __builtin_nontemporal_load(&col[p]);
        if (p + 12 < e1) s1 = __builtin_nontemporal_load(&col[p + 12]);
        if (p + 24 < e1) s2 = __builtin_nontemporal_load(&col[p + 24]);
        if (p + 36 < e1) s3 = __builtin_nontemporal_load(&col[p + 36]);
    }
    bool p0 = s0 >= 0, p1 = s1 >= 0, p2 = s2 >= 0, p3 = s3 >= 0;
    float4 v0 = y4[(p0 ? s0 : n) * 5 + jq];
    float4 v1 = y4[(p1 ? s1 : n) * 5 + jq];
    float4 v2 = y4[(p2 ? s2 : n) * 5 + jq];
    float4 v3 = y4[(p3 ? s3 : n) * 5 + jq];

    double g[4] = {0.0, 0.0, 0.0, 0.0};
    if (ep == 0) {               // self loop handled by slot 0
        float4 v = y4[n * 5 + jq];
        g[0] = (double)v.x; g[1] = (double)v.y; g[2] = (double)v.z; g[3] = (double)v.w;
    }
    if (p0) { g[0] += (double)v0.x; g[1] += (double)v0.y; g[2] += (double)v0.z; g[3] += (double)v0.w; }
    if (p1) { g[0] += (double)v1.x; g[1] += (double)v1.y; g[2] += (double)v1.z; g[3] += (double)v1.w; }
    if (p2) { g[0] += (double)v2.x; g[1] += (double)v2.y; g[2] += (double)v2.z; g[3] += (double)v2.w; }
    if (p3) { g[0] += (double)v3.x; g[1] += (double)v3.y; g[2] += (double)v3.z; g[3] += (double)v3.w; }

    // rare tail: deg > 48 (wave-uniform branch)
    if (e1 - e0 > 48) {
        if (ep < 12) {
            for (int e = e0 + 48 + ep; e < e1; e += 12) {
                int s = __builtin_nontemporal_load(&col[e]);
                float4 v = y4[s * 5 + jq];
                g[0] += (double)v.x; g[1] += (double)v.y;
                g[2] += (double)v.z; g[3] += (double)v.w;
            }
        }
    }

    // fold 12 edge slots down to slot 0 in f32 (half the ds_bpermute traffic)
    float f0 = (float)g[0], f1 = (float)g[1], f2 = (float)g[2], f3 = (float)g[3];
#define FOLD(LIM, DELTA)                                                        \
    {                                                                           \
        int srcl = lane + DELTA; if (srcl > 63) srcl = lane;                    \
        float t0 = __shfl(f0, srcl, 64);                                        \
        float t1 = __shfl(f1, srcl, 64);                                        \
        float t2 = __shfl(f2, srcl, 64);                                        \
        float t3 = __shfl(f3, srcl, 64);                                        \
        if (ep < (LIM)) { f0 += t0; f1 += t1; f2 += t2; f3 += t3; }             \
    }
    FOLD(4, 40)   // ep(0..3)  += ep+8
    FOLD(4, 20)   // ep(0..3)  += ep+4
    FOLD(2, 10)   // ep(0..1)  += ep+2
    FOLD(1, 5)    // ep(0)     += ep+1
#undef FOLD

    if (lane < 5) {
        double dn = din[n];
        float4 bb = ((const float4*)b)[lane];    // b row is 16B-aligned (80B stride)
        double o0 = (double)f0 * dn + (double)bb.x;
        double o1 = (double)f1 * dn + (double)bb.y;
        double o2 = (double)f2 * dn + (double)bb.z;
        double o3 = (double)f3 * dn + (double)bb.w;
        float4 w;
        if (mode == 0) {
            double dd = dout[n];
            w.x = (float)((double)fmaxf((float)o0, 0.0f) * dd);
            w.y = (float)((double)fmaxf((float)o1, 0.0f) * dd);
            w.z = (float)((double)fmaxf((float)o2, 0.0f) * dd);
            w.w = (float)((double)fmaxf((float)o3, 0.0f) * dd);
        } else {
            w.x = (float)o0; w.y = (float)o1; w.z = (float)o2; w.w = (float)o3;
        }
        ((float4*)(hout + (size_t)n * DH))[lane] = w;   // 5 lanes x 16B = 80B row
    }
}

// ---------------- launch ----------------

static inline size_t align256(size_t x) { return (x + 255) & ~(size_t)255; }

extern "C" void kernel_launch(void* const* d_in, const int* in_sizes, int n_in,
                              void* d_out, int out_size, void* d_ws, size_t ws_size,
                              hipStream_t stream) {
    const float* feat    = (const float*)d_in[0];
    const float* W_start = (const float*)d_in[1];
    const float* b_start = (const float*)d_in[2];
    const float* W_mid   = (const float*)d_in[3];
    const float* b_mid   = (const float*)d_in[4];
    const float* W_final = (const float*)d_in[5];
    const float* b_final = (const float*)d_in[6];
    const int*   src     = (const int*)d_in[7];
    const int*   dst     = (const int*)d_in[8];

    const int N = in_sizes[0];              // 100000
    const int E = in_sizes[7];              // 3200000
    const int L = in_sizes[3] / (DH * DH);  // 18 mid layers
    const int KC = (N + BKC - 1) / BKC;     // coarse buckets (98)
    const int KF = (N + BKF - 1) / BKF;     // fine buckets (391)
    const int NB = (E + CHUNK - 1) / CHUNK; // chunk blocks (391)

    // workspace carve-up
    char* p = (char*)d_ws;
    double* dout_d = (double*)p; p += align256(sizeof(double) * N);
    double* din_d  = (double*)p; p += align256(sizeof(double) * N);
    double* x0     = (double*)p; p += align256(sizeof(double) * N);
    int* row_ptr   = (int*)p;    p += align256(sizeof(int) * (N + 1));
    int* bbase_d   = (int*)p;    p += align256(sizeof(int) * (MAXKC + 1));
    int* bbase_s   = (int*)p;    p += align256(sizeof(int) * (MAXKC + 1));
    int* pbh_d     = (int*)p;    p += align256(sizeof(int) * MAXNB * MAXKC);
    int* pbh_s     = (int*)p;    p += align256(sizeof(int) * MAXNB * MAXKC);
    int* col       = (int*)p;    p += align256(sizeof(int) * E);
    float* hbuf    = (float*)p;  p += align256(sizeof(float) * N * DH);
    float* ybuf    = (float*)p;  p += align256(sizeof(float) * N * DH);
    // pairs (E ints = 12.8MB) overlays hbuf+ybuf (16MB); dead before layer_start
    int* pairs = (int*)hbuf;
    // ssort (E ints) aliases col: consumed by bucket_outdeg BEFORE bucket_build
    // overwrites the region with the real CSR
    int* ssort = col;

    const int BT = 256;
    int grid_n  = (N + BT - 1) / BT;
    int grid_nw = (N + 3) / 4;              // 1 wave per node, 4 waves per block

    // ---- graph setup ----
    bucket_hist2<<<NB, BT, 0, stream>>>(src, dst, pbh_d, pbh_s, E, KC);
    pb_scan<<<1, 256, 0, stream>>>(pbh_d, pbh_s, bbase_d, bbase_s, NB, KC);
    bucket_place<<<NB, BT, 0, stream>>>(src, dst, pbh_d, pbh_s, pairs, ssort, E, KC);
    bucket_outdeg<<<KC, BT, 0, stream>>>(bbase_s, ssort, dout_d, N);
    bucket_build<<<KF, BT, 0, stream>>>(bbase_d, pairs, row_ptr, din_d, col, N, E);

    // ---- layer 0 (scalar input) ----
    compute_x0<<<grid_n, BT, 0, stream>>>(feat, dout_d, x0, N);
    layer_start<<<grid_nw, BT, 0, stream>>>(x0, row_ptr, col, din_d, dout_d,
                                            W_start, b_start, hbuf, N);

    // ---- 18 mid layers: dense transform + gather-aggregate ----
    for (int l = 0; l < L; ++l) {
        transform<<<grid_n, BT, 0, stream>>>(hbuf, W_mid + (size_t)l * DH * DH, ybuf, N);
        gather_agg<<<grid_nw, BT, 0, stream>>>(ybuf, row_ptr, col, din_d, dout_d,
                                               b_mid + (size_t)l * DH, hbuf, N, 0);
    }

    // ---- final layer: raw store to d_out ----
    transform<<<grid_n, BT, 0, stream>>>(hbuf, W_final, ybuf, N);
    gather_agg<<<grid_nw, BT, 0, stream>>>(ybuf, row_ptr, col, din_d, dout_d,
                                           b_final, (float*)d_out, N, 1);
}

// Round 8
// 1631.272 us; speedup vs baseline: 1.0471x; 1.0471x over previous
//
#include <hip/hip_runtime.h>

#define DH    20       // hidden width
#define BKSC  10       // log2 nodes per COARSE bucket (sort granularity)
#define BKC   1024     // nodes per coarse bucket
#define MAXKC 128      // max coarse buckets (N=100000 -> KC=98)
#define MAXNB 512      // max chunk blocks (E=3.2M/8192 -> 391)
#define BKSF  8        // log2 nodes per FINE bucket (build granularity)
#define BKF   256      // nodes per fine bucket
#define ECAP  10240    // LDS col-staging capacity per fine bucket (avg ~8.2K)
#define CHUNK 8192     // edges per hist/place block

// ---------------- setup kernels ----------------

__global__ void zero_bhist2(int* __restrict__ bhist_d, int* __restrict__ bhist_s) {
    int i = threadIdx.x;
    if (i < MAXKC) { bhist_d[i] = 0; bhist_s[i] = 0; }
}

// one read pass over src+dst; per-block histograms to pbh (global, coalesced)
// + bucket totals via ~98x2 global atomics per block (negligible)
__global__ __launch_bounds__(256) void bucket_hist2(const int* __restrict__ src,
        const int* __restrict__ dst, int* __restrict__ pbh_d,
        int* __restrict__ pbh_s, int* __restrict__ bhist_d,
        int* __restrict__ bhist_s, int E, int K) {
    __shared__ int hd[MAXKC];
    __shared__ int hs[MAXKC];
    for (int i = threadIdx.x; i < K; i += blockDim.x) { hd[i] = 0; hs[i] = 0; }
    __syncthreads();
    int lo = blockIdx.x * CHUNK;
    int hi = lo + CHUNK; if (hi > E) hi = E;
    for (int e = lo + (int)threadIdx.x; e < hi; e += 256) {
        atomicAdd(&hd[__builtin_nontemporal_load(&dst[e]) >> BKSC], 1);
        atomicAdd(&hs[__builtin_nontemporal_load(&src[e]) >> BKSC], 1);
    }
    __syncthreads();
    for (int i = threadIdx.x; i < K; i += blockDim.x) {
        pbh_d[blockIdx.x * MAXKC + i] = hd[i];
        pbh_s[blockIdx.x * MAXKC + i] = hs[i];
        if (hd[i]) atomicAdd(&bhist_d[i], hd[i]);
        if (hs[i]) atomicAdd(&bhist_s[i], hs[i]);
    }
}

// parallel exclusive scan of both bucket-total arrays (K <= 128), single block
__global__ __launch_bounds__(128) void bucket_scan2(
        const int* __restrict__ bhist_d, int* __restrict__ bbase_d,
        int* __restrict__ bcursor_d, const int* __restrict__ bhist_s,
        int* __restrict__ bbase_s, int* __restrict__ bcursor_s, int K) {
    __shared__ int a[MAXKC];
    __shared__ int b[MAXKC];
    int t = threadIdx.x;
    int vd = (t < K) ? bhist_d[t] : 0;
    int vs = (t < K) ? bhist_s[t] : 0;
    a[t] = vd; b[t] = vs;
    __syncthreads();
    for (int off = 1; off < 128; off <<= 1) {
        int x = (t >= off) ? a[t - off] : 0;
        int y = (t >= off) ? b[t - off] : 0;
        __syncthreads();
        a[t] += x; b[t] += y;
        __syncthreads();
    }
    if (t < K) {
        int ed = a[t] - vd, es = b[t] - vs;
        bbase_d[t] = ed; bcursor_d[t] = ed;
        bbase_s[t] = es; bcursor_s[t] = es;
    }
    if (t == K - 1) { bbase_d[K] = a[t]; bbase_s[K] = b[t]; }
}

// one-pass counting place: per-block run reservation via ONE global atomicAdd
// per (block,bucket) using the precomputed pbh counts (no re-histogram), then
// scatter with LDS cursors. Within-bucket order is arbitrary — downstream
// consumers only need bucket-contiguity. pairs = (src<<10|dst&1023)
// dst-sorted; ssort = src&1023 src-sorted.
__global__ __launch_bounds__(256) void bucket_place(const int* __restrict__ src,
        const int* __restrict__ dst, const int* __restrict__ pbh_d,
        const int* __restrict__ pbh_s, int* __restrict__ bcursor_d,
        int* __restrict__ bcursor_s, int* __restrict__ pairs,
        int* __restrict__ ssort, int E, int K) {
    __shared__ int cd[MAXKC];
    __shared__ int cs[MAXKC];
    for (int i = threadIdx.x; i < K; i += blockDim.x) {
        int nd = pbh_d[blockIdx.x * MAXKC + i];
        int ns = pbh_s[blockIdx.x * MAXKC + i];
        cd[i] = nd ? atomicAdd(&bcursor_d[i], nd) : 0;
        cs[i] = ns ? atomicAdd(&bcursor_s[i], ns) : 0;
    }
    __syncthreads();
    int lo = blockIdx.x * CHUNK;
    int hi = lo + CHUNK; if (hi > E) hi = E;
    for (int e = lo + (int)threadIdx.x; e < hi; e += 256) {
        int d = __builtin_nontemporal_load(&dst[e]);
        int s = __builtin_nontemporal_load(&src[e]);
        int pd = atomicAdd(&cd[d >> BKSC], 1);          // LDS atomic
        pairs[pd] = (s << BKSC) | (d & (BKC - 1));      // src<2^17 -> 27 bits
        int ps = atomicAdd(&cs[s >> BKSC], 1);
        ssort[ps] = s & (BKC - 1);
    }
}

// per-coarse-src-bucket LDS histogram over its ssort segment -> dout
__global__ __launch_bounds__(256) void bucket_outdeg(const int* __restrict__ bbase_s,
        const int* __restrict__ ssort, double* __restrict__ dout, int n_nodes) {
    __shared__ int h[BKC];
    int k = blockIdx.x;
    int t = threadIdx.x;
    int nbase = k << BKSC;
    int nrem = n_nodes - nbase; if (nrem > BKC) nrem = BKC;
    for (int i = t; i < BKC; i += 256) h[i] = 1;   // self loop
    __syncthreads();
    int e0 = bbase_s[k], e1 = bbase_s[k + 1];
    for (int e = e0 + t; e < e1; e += 256)
        atomicAdd(&h[__builtin_nontemporal_load(&ssort[e])], 1);
    __syncthreads();
    for (int i = t; i < nrem; i += 256)
        dout[nbase + i] = 1.0 / sqrt((double)h[i]);
}

// FINE-granularity build (391 blocks for occupancy) over the COARSE-sorted
// pairs: fine block k filters its quarter of coarse segment k>>2 in two
// L2-hot passes. Pass 1: fine histogram + 'before' count -> global base.
// Block scan -> row_ptr + din. Pass 2: scatter into LDS staging, stream out
// as contiguous full lines. XCD-chunked swizzle keeps sibling fine blocks on
// one XCD so the coarse segment stays L2-resident.
__global__ __launch_bounds__(256) void bucket_build(
        const int* __restrict__ bbase, const int* __restrict__ pairs,
        int* __restrict__ row_ptr, double* __restrict__ din,
        int* __restrict__ col, int n_nodes, int n_edges) {
    __shared__ int h[BKF];
    __shared__ int ts[BKF];
    __shared__ int red[256];
    __shared__ int ecol[ECAP];
    int nwg = gridDim.x;
    int xcd = blockIdx.x & 7;
    int loc = blockIdx.x >> 3;
    int q = nwg >> 3, r = nwg & 7;
    int k = ((xcd < r) ? xcd * (q + 1) : r * (q + 1) + (xcd - r) * q) + loc;
    int kc = k >> 2;             // coarse bucket
    int f  = k & 3;              // quarter within coarse bucket
    int t = threadIdx.x;
    int nbase = k << BKSF;
    int nrem = n_nodes - nbase; if (nrem > BKF) nrem = BKF;
    h[t] = 0;
    __syncthreads();
    int e0 = bbase[kc], e1 = bbase[kc + 1];
    int before = 0;
    for (int e = e0 + t; e < e1; e += 256) {
        int pk = pairs[e];                    // plain load: re-read, keep cached
        int dl = pk & (BKC - 1);
        int fe = dl >> BKSF;
        if (fe == f) atomicAdd(&h[dl & (BKF - 1)], 1);
        else if (fe < f) ++before;
    }
    red[t] = before;
    __syncthreads();
    for (int off = 128; off > 0; off >>= 1) {
        if (t < off) red[t] += red[t + off];
        __syncthreads();
    }
    int fbase = e0 + red[0];                  // global base of this fine segment
    int c = h[t];
    ts[t] = c;
    __syncthreads();
    for (int off = 1; off < 256; off <<= 1) {
        int v = (t >= off) ? ts[t - off] : 0;
        __syncthreads();
        ts[t] += v;
        __syncthreads();
    }
    int lx = ts[t] - c;                       // fine-local exclusive prefix
    if (t < nrem) {
        row_ptr[nbase + t] = fbase + lx;
        din[nbase + t] = 1.0 / sqrt((double)(c + 1));   // +1 self loop
    }
    h[t] = lx;                                // fine-local cursor into ecol
    if (t == 0 && nbase + BKF >= n_nodes) row_ptr[n_nodes] = n_edges;
    __syncthreads();
    for (int e = e0 + t; e < e1; e += 256) {
        int pk = pairs[e];
        int dl = pk & (BKC - 1);
        if ((dl >> BKSF) == f) {
            int slot = atomicAdd(&h[dl & (BKF - 1)], 1);    // LDS atomic
            if (slot < ECAP) ecol[slot] = pk >> BKSC;
            else col[fbase + slot] = pk >> BKSC;            // overflow guard
        }
    }
    __syncthreads();
    int cnt = ts[BKF - 1];
    int lim = cnt < ECAP ? cnt : ECAP;
    for (int i = t; i < lim; i += 256)        // contiguous full-line stream-out
        col[fbase + i] = ecol[i];
}

// ---------------- layer kernels ----------------

// x0[n] = feat[n] * dout[n]   (layer 0 input is N x 1)
__global__ void compute_x0(const float* __restrict__ feat, const double* __restrict__ dout,
                           double* __restrict__ x0, int n) {
    int i = blockIdx.x * blockDim.x + threadIdx.x;
    if (i < n) x0[i] = (double)feat[i] * dout[i];
}

// layer 0: g[n] = x0[n] + sum_{s in N(n)} x0[s]  (scalar gather, 64 lanes edge-parallel)
__global__ __launch_bounds__(256) void layer_start(
        const double* __restrict__ x0, const int* __restrict__ row_ptr,
        const int* __restrict__ col, const double* __restrict__ din,
        const double* __restrict__ dout, const float* __restrict__ W,
        const float* __restrict__ b, float* __restrict__ xout, int n_nodes) {
    int n    = (blockIdx.x * blockDim.x + threadIdx.x) >> 6;   // one wave per node
    int lane = threadIdx.x & 63;
    if (n >= n_nodes) return;
    double a = (lane == 0) ? x0[n] : 0.0;   // self loop
    int e0 = row_ptr[n], e1 = row_ptr[n + 1];
    for (int e = e0 + lane; e < e1; e += 64)
        a += x0[__builtin_nontemporal_load(&col[e])];
#pragma unroll
    for (int off = 32; off > 0; off >>= 1)
        a += __shfl_xor(a, off, 64);
    if (lane < DH) {
        double v = a * din[n] * (double)W[lane] + (double)b[lane];
        float r = fmaxf((float)v, 0.0f);
        xout[(long)n * DH + lane] = (float)((double)r * dout[n]);
    }
}

// dense transform: y[n] = h'[n] @ W   (h' already carries the dout scaling).
__global__ __launch_bounds__(256) void transform(
        const float* __restrict__ h, const float* __restrict__ W,
        float* __restrict__ y, int n_nodes) {
    __shared__ float Wl[DH * DH];
    for (int i = threadIdx.x; i < DH * DH; i += blockDim.x) Wl[i] = W[i];
    __syncthreads();
    int n = blockIdx.x * blockDim.x + threadIdx.x;
    if (n >= n_nodes) return;
    const float4* h4 = (const float4*)(h + (size_t)n * DH);
    float4 a0 = h4[0], a1 = h4[1], a2 = h4[2], a3 = h4[3], a4 = h4[4];
    float hv[DH] = {a0.x, a0.y, a0.z, a0.w, a1.x, a1.y, a1.z, a1.w,
                    a2.x, a2.y, a2.z, a2.w, a3.x, a3.y, a3.z, a3.w,
                    a4.x, a4.y, a4.z, a4.w};
    double acc[DH];
#pragma unroll
    for (int j = 0; j < DH; ++j) acc[j] = 0.0;
#pragma unroll
    for (int k = 0; k < DH; ++k) {
        double hk = (double)hv[k];
#pragma unroll
        for (int j = 0; j < DH; ++j)
            acc[j] += hk * (double)Wl[k * DH + j];   // LDS broadcast, conflict-free
    }
    float4* y4 = (float4*)(y + (size_t)n * DH);
    y4[0] = make_float4((float)acc[0],  (float)acc[1],  (float)acc[2],  (float)acc[3]);
    y4[1] = make_float4((float)acc[4],  (float)acc[5],  (float)acc[6],  (float)acc[7]);
    y4[2] = make_float4((float)acc[8],  (float)acc[9],  (float)acc[10], (float)acc[11]);
    y4[3] = make_float4((float)acc[12], (float)acc[13], (float)acc[14], (float)acc[15]);
    y4[4] = make_float4((float)acc[16], (float)acc[17], (float)acc[18], (float)acc[19]);
}

// gather+aggregate: h'[n] = relu(din[n]*(y[n] + sum_{s in N(n)} y[s]) + b) * dout[n]
// Per-slot accumulation in f64; single convert to f32 before the folds halves
// the cross-lane traffic (shfl double = 2 ds_bpermute; f32 = 1).
__global__ __launch_bounds__(256, 8) void gather_agg(
        const float* __restrict__ y, const int* __restrict__ row_ptr,
        const int* __restrict__ col, const double* __restrict__ din,
        const double* __restrict__ dout, const float* __restrict__ b,
        float* __restrict__ hout, int n_nodes, int mode) {
    int n    = (blockIdx.x * blockDim.x + threadIdx.x) >> 6;   // one wave per node
    int lane = threadIdx.x & 63;
    if (n >= n_nodes) return;

    int ep = lane / 5;           // edge slot 0..12 (lanes 60..63 -> ep=12, inactive)
    int jq = lane - ep * 5;      // float4 quarter 0..4
    const float4* __restrict__ y4 = (const float4*)y;

    int e0 = row_ptr[n], e1 = row_ptr[n + 1];

    int s0 = -1, s1 = -1, s2 = -1, s3 = -1;
    if (ep < 12) {
        int p = e0 + ep;
        if (p      < e1) s0 = __builtin_nontemporal_load(&col[p]);
        if (p + 12 < e1) s1 = __builtin_nontemporal_load(&col[p + 12]);
        if (p + 24 < e1) s2 = __builtin_nontemporal_load(&col[p + 24]);
        if (p + 36 < e1) s3 = __builtin_nontemporal_load(&col[p + 36]);
    }
    bool p0 = s0 >= 0, p1 = s1 >= 0, p2 = s2 >= 0, p3 = s3 >= 0;
    float4 v0 = y4[(p0 ? s0 : n) * 5 + jq];
    float4 v1 = y4[(p1 ? s1 : n) * 5 + jq];
    float4 v2 = y4[(p2 ? s2 : n) * 5 + jq];
    float4 v3 = y4[(p3 ? s3 : n) * 5 + jq];

    double g[4] = {0.0, 0.0, 0.0, 0.0};
    if (ep == 0) {               // self loop handled by slot 0
        float4 v = y4[n * 5 + jq];
        g[0] = (double)v.x; g[1] = (double)v.y; g[2] = (double)v.z; g[3] = (double)v.w;
    }
    if (p0) { g[0] += (double)v0.x; g[1] += (double)v0.y; g[2] += (double)v0.z; g[3] += (double)v0.w; }
    if (p1) { g[0] += (double)v1.x; g[1] += (double)v1.y; g[2] += (double)v1.z; g[3] += (double)v1.w; }
    if (p2) { g[0] += (double)v2.x; g[1] += (double)v2.y; g[2] += (double)v2.z; g[3] += (double)v2.w; }
    if (p3) { g[0] += (double)v3.x; g[1] += (double)v3.y; g[2] += (double)v3.z; g[3] += (double)v3.w; }

    // rare tail: deg > 48 (wave-uniform branch)
    if (e1 - e0 > 48) {
        if (ep < 12) {
            for (int e = e0 + 48 + ep; e < e1; e += 12) {
                int s = __builtin_nontemporal_load(&col[e]);
                float4 v = y4[s * 5 + jq];
                g[0] += (double)v.x; g[1] += (double)v.y;
                g[2] += (double)v.z; g[3] += (double)v.w;
            }
        }
    }

    // fold 12 edge slots down to slot 0 in f32 (half the ds_bpermute traffic)
    float f0 = (float)g[0], f1 = (float)g[1], f2 = (float)g[2], f3 = (float)g[3];
#define FOLD(LIM, DELTA)                                                        \
    {                                                                           \
        int srcl = lane + DELTA; if (srcl > 63) srcl = lane;                    \
        float t0 = __shfl(f0, srcl, 64);                                        \
        float t1 = __shfl(f1, srcl, 64);                                        \
        float t2 = __shfl(f2, srcl, 64);                                        \
        float t3 = __shfl(f3, srcl, 64);                                        \
        if (ep < (LIM)) { f0 += t0; f1 += t1; f2 += t2; f3 += t3; }             \
    }
    FOLD(4, 40)   // ep(0..3)  += ep+8
    FOLD(4, 20)   // ep(0..3)  += ep+4
    FOLD(2, 10)   // ep(0..1)  += ep+2
    FOLD(1, 5)    // ep(0)     += ep+1
#undef FOLD

    if (lane < 5) {
        double dn = din[n];
        float4 bb = ((const float4*)b)[lane];    // b row is 16B-aligned (80B stride)
        double o0 = (double)f0 * dn + (double)bb.x;
        double o1 = (double)f1 * dn + (double)bb.y;
        double o2 = (double)f2 * dn + (double)bb.z;
        double o3 = (double)f3 * dn + (double)bb.w;
        float4 w;
        if (mode == 0) {
            double dd = dout[n];
            w.x = (float)((double)fmaxf((float)o0, 0.0f) * dd);
            w.y = (float)((double)fmaxf((float)o1, 0.0f) * dd);
            w.z = (float)((double)fmaxf((float)o2, 0.0f) * dd);
            w.w = (float)((double)fmaxf((float)o3, 0.0f) * dd);
        } else {
            w.x = (float)o0; w.y = (float)o1; w.z = (float)o2; w.w = (float)o3;
        }
        ((float4*)(hout + (size_t)n * DH))[lane] = w;   // 5 lanes x 16B = 80B row
    }
}

// ---------------- launch ----------------

static inline size_t align256(size_t x) { return (x + 255) & ~(size_t)255; }

extern "C" void kernel_launch(void* const* d_in, const int* in_sizes, int n_in,
                              void* d_out, int out_size, void* d_ws, size_t ws_size,
                              hipStream_t stream) {
    const float* feat    = (const float*)d_in[0];
    const float* W_start = (const float*)d_in[1];
    const float* b_start = (const float*)d_in[2];
    const float* W_mid   = (const float*)d_in[3];
    const float* b_mid   = (const float*)d_in[4];
    const float* W_final = (const float*)d_in[5];
    const float* b_final = (const float*)d_in[6];
    const int*   src     = (const int*)d_in[7];
    const int*   dst     = (const int*)d_in[8];

    const int N = in_sizes[0];              // 100000
    const int E = in_sizes[7];              // 3200000
    const int L = in_sizes[3] / (DH * DH);  // 18 mid layers
    const int KC = (N + BKC - 1) / BKC;     // coarse buckets (98)
    const int KF = (N + BKF - 1) / BKF;     // fine buckets (391)
    const int NB = (E + CHUNK - 1) / CHUNK; // chunk blocks (391)

    // workspace carve-up
    char* p = (char*)d_ws;
    double* dout_d = (double*)p; p += align256(sizeof(double) * N);
    double* din_d  = (double*)p; p += align256(sizeof(double) * N);
    double* x0     = (double*)p; p += align256(sizeof(double) * N);
    int* row_ptr   = (int*)p;    p += align256(sizeof(int) * (N + 1));
    int* bhist_d   = (int*)p;    p += align256(sizeof(int) * (MAXKC + 1));
    int* bhist_s   = (int*)p;    p += align256(sizeof(int) * (MAXKC + 1));
    int* bbase_d   = (int*)p;    p += align256(sizeof(int) * (MAXKC + 1));
    int* bbase_s   = (int*)p;    p += align256(sizeof(int) * (MAXKC + 1));
    int* bcursor_d = (int*)p;    p += align256(sizeof(int) * (MAXKC + 1));
    int* bcursor_s = (int*)p;    p += align256(sizeof(int) * (MAXKC + 1));
    int* pbh_d     = (int*)p;    p += align256(sizeof(int) * MAXNB * MAXKC);
    int* pbh_s     = (int*)p;    p += align256(sizeof(int) * MAXNB * MAXKC);
    int* col       = (int*)p;    p += align256(sizeof(int) * E);
    float* hbuf    = (float*)p;  p += align256(sizeof(float) * N * DH);
    float* ybuf    = (float*)p;  p += align256(sizeof(float) * N * DH);
    // pairs (E ints = 12.8MB) overlays hbuf+ybuf (16MB); dead before layer_start
    int* pairs = (int*)hbuf;
    // ssort (E ints) aliases col: consumed by bucket_outdeg BEFORE bucket_build
    // overwrites the region with the real CSR
    int* ssort = col;

    const int BT = 256;
    int grid_n  = (N + BT - 1) / BT;
    int grid_nw = (N + 3) / 4;              // 1 wave per node, 4 waves per block

    // ---- graph setup ----
    zero_bhist2<<<1, MAXKC, 0, stream>>>(bhist_d, bhist_s);
    bucket_hist2<<<NB, BT, 0, stream>>>(src, dst, pbh_d, pbh_s,
                                        bhist_d, bhist_s, E, KC);
    bucket_scan2<<<1, 128, 0, stream>>>(bhist_d, bbase_d, bcursor_d,
                                        bhist_s, bbase_s, bcursor_s, KC);
    bucket_place<<<NB, BT, 0, stream>>>(src, dst, pbh_d, pbh_s,
                                        bcursor_d, bcursor_s, pairs, ssort, E, KC);
    bucket_outdeg<<<KC, BT, 0, stream>>>(bbase_s, ssort, dout_d, N);
    bucket_build<<<KF, BT, 0, stream>>>(bbase_d, pairs, row_ptr, din_d, col, N, E);

    // ---- layer 0 (scalar input) ----
    compute_x0<<<grid_n, BT, 0, stream>>>(feat, dout_d, x0, N);
    layer_start<<<grid_nw, BT, 0, stream>>>(x0, row_ptr, col, din_d, dout_d,
                                            W_start, b_start, hbuf, N);

    // ---- 18 mid layers: dense transform + gather-aggregate ----
    for (int l = 0; l < L; ++l) {
        transform<<<grid_n, BT, 0, stream>>>(hbuf, W_mid + (size_t)l * DH * DH, ybuf, N);
        gather_agg<<<grid_nw, BT, 0, stream>>>(ybuf, row_ptr, col, din_d, dout_d,
                                               b_mid + (size_t)l * DH, hbuf, N, 0);
    }

    // ---- final layer: raw store to d_out ----
    transform<<<grid_n, BT, 0, stream>>>(hbuf, W_final, ybuf, N);
    gather_agg<<<grid_nw, BT, 0, stream>>>(ybuf, row_ptr, col, din_d, dout_d,
                                           b_final, (float*)d_out, N, 1);
}